// Round 6
// baseline (496.447 us; speedup 1.0000x reference)
//
#include <hip/hip_runtime.h>
#include <hip/hip_fp16.h>

// DimCL encoder, R12.
//  - spmm: consecutive-slot mapping -- slot s (=lane>>3) owns edges
//    j+4s..j+4s+3, so its 4 records are 32B contiguous: 2 x int4 record
//    loads per lane (halves record lane-requests vs 4 x int2). Row segments
//    even-aligned in erec (k_csr pads counts to even) so int4 loads are
//    16B-aligned.
//  - spmm: fast/slow-path predication. Fully-valid slots take the fast path
//    (4 gathers back-to-back + 32 fma_mix: full MLP); slots past row end
//    issue ZERO gather requests; the one boundary slot per row takes a
//    per-edge guarded path. ~44% fewer lane-requests per row overall.
//  - build: k_part1 unchanged (R10/R11 form); k_csr scan now rounds row
//    counts up to even (pad slots never referenced as valid).
// Layers fp16, all math fp32.

#define CSH 8             // 256 rows per coarse bin
#define CBROWS (1 << CSH)
#define CAPC 6144         // bin capacity (avg ~5120, ~14 sigma slack)
#define T1 4096           // edges per k_part1 block tile
#define EPT 8             // edges per thread in k_part1 (T1 = 512*EPT)
#define COLMASK 0x3FFFF   // n_nodes < 2^18

// acc += (float)lo_half(pk) * v   /   acc += (float)hi_half(pk) * v
#define FMAMIX_LO(acc, pk, v)                                             \
  asm("v_fma_mix_f32 %0, %1, %2, %0 op_sel:[0,0,0] op_sel_hi:[1,0,0]"     \
      : "+v"(acc)                                                         \
      : "v"(pk), "v"(v))
#define FMAMIX_HI(acc, pk, v)                                             \
  asm("v_fma_mix_f32 %0, %1, %2, %0 op_sel:[1,0,0] op_sel_hi:[1,0,0]"     \
      : "+v"(acc)                                                         \
      : "v"(pk), "v"(v))

#define FMA8(g, v)                                                        \
  do {                                                                    \
    FMAMIX_LO(c0, (g).x, (v)); FMAMIX_HI(c1, (g).x, (v));                 \
    FMAMIX_LO(c2, (g).y, (v)); FMAMIX_HI(c3, (g).y, (v));                 \
    FMAMIX_LO(c4, (g).z, (v)); FMAMIX_HI(c5, (g).z, (v));                 \
    FMAMIX_LO(c6, (g).w, (v)); FMAMIX_HI(c7, (g).w, (v));                 \
  } while (0)

__device__ __forceinline__ int wave_iscan(int v, int lane) {
#pragma unroll
  for (int off = 1; off < 64; off <<= 1) {
    int t = __shfl_up(v, off, 64);
    if (lane >= off) v += t;
  }
  return v;
}

// Coarse multi-split, 512 threads: fused ego convert, then per-block LDS
// histogram + scan + reserve + reorder, bin-sorted copy-out to staging.
// Requires NC <= 1024 (n_nodes <= 262144).
__global__ __launch_bounds__(512) void k_part1(
    const int* __restrict__ rows, const int* __restrict__ cols,
    const float* __restrict__ vals, int* __restrict__ ccur,
    int2* __restrict__ cstag, int E,
    const float* __restrict__ ue, const float* __restrict__ ie,
    __half* __restrict__ h0, int nuser_e, int total_e) {
  __shared__ int cnt[1024];   // counts; after reserve, holds global bases
  __shared__ int offs[1024];
  __shared__ int lcur[1024];
  __shared__ int wsum8[8];
  __shared__ int2 sout[T1];
  __shared__ unsigned short sbin[T1];
  int tid = threadIdx.x;
  int lane = tid & 63, wid = tid >> 6;
  int base = blockIdx.x * T1;

  // fused ego init (streaming; overlaps other blocks' latency phases)
  for (int i = blockIdx.x * 512 + tid; i < total_e; i += gridDim.x * 512) {
    float x = (i < nuser_e) ? ue[i] : ie[i - nuser_e];
    h0[i] = __float2half(x);
  }

  cnt[tid] = 0;
  cnt[tid + 512] = 0;
  __syncthreads();

  int recx[EPT], recy[EPT], rbin[EPT];
#pragma unroll
  for (int k = 0; k < EPT; ++k) {
    int idx = base + k * 512 + tid;
    if (idx < E) {
      int r = rows[idx];
      int b = r >> CSH;
      recx[k] = cols[idx] | ((r & (CBROWS - 1)) << 18);
      recy[k] = __float_as_int(vals[idx]);
      rbin[k] = b;
      atomicAdd(&cnt[b], 1);
    } else {
      rbin[k] = -1;
    }
  }
  __syncthreads();

  // exclusive scan of 1024 counters: thread t owns slots 2t, 2t+1.
  int c0 = cnt[2 * tid], c1 = cnt[2 * tid + 1];
  int s = c0 + c1;
  int incl = wave_iscan(s, lane);
  if (lane == 63) wsum8[wid] = incl;
  __syncthreads();
  if (wid == 0) {
    int t = (lane < 8) ? wsum8[lane] : 0;
    t = wave_iscan(t, lane);
    if (lane < 8) wsum8[lane] = t;
  }
  __syncthreads();
  int woff = wid ? wsum8[wid - 1] : 0;
  incl += woff;
  int e0 = incl - s;
  offs[2 * tid] = e0;
  offs[2 * tid + 1] = e0 + c0;
  lcur[2 * tid] = e0;
  lcur[2 * tid + 1] = e0 + c0;
  __syncthreads();

  // reserve contiguous global ranges per bin; store base over cnt (each slot
  // read+written by the same thread -> no hazard).
#pragma unroll
  for (int j = 0; j < 2; ++j) {
    int t = tid + 512 * j;
    int c = cnt[t];
    if (c > 0) cnt[t] = atomicAdd(&ccur[t], c);
  }
  // bin-sorted reorder into LDS.
#pragma unroll
  for (int k = 0; k < EPT; ++k) {
    if (rbin[k] >= 0) {
      int p = atomicAdd(&lcur[rbin[k]], 1);
      sout[p] = make_int2(recx[k], recy[k]);
      sbin[p] = (unsigned short)rbin[k];
    }
  }
  __syncthreads();

  // run-coalesced copy-out: consecutive i -> same bin -> consecutive addrs.
  int m = min(T1, E - base);
  for (int i = tid; i < m; i += 512) {
    int b = sbin[i];
    int rel = cnt[b] + (i - offs[b]);  // cnt[] holds global base now
    if (rel < CAPC) cstag[(size_t)b * CAPC + rel] = sout[i];
  }
}

// Fused CSR finalize: one block per bin. Bin base from a global atomic
// cursor. Row counts rounded UP TO EVEN in the scan so every row segment
// starts at an even record index (16B alignment for spmm's int4 record
// loads); pad slots are never referenced as valid. Stage records in LDS
// (int4 = 2 records per load), per-row hist, in-block scan, scatter to
// final erec (bin's contiguous ~40KB chunk, L2-resident), write per-row
// (start,end) int2.
__global__ __launch_bounds__(512) void k_csr(
    const int2* __restrict__ cstag, const int* __restrict__ ccur,
    int* __restrict__ gcur, int2* __restrict__ erec,
    int2* __restrict__ ptr2, int n_nodes) {
  __shared__ int2 srec[CAPC];     // 48KB
  __shared__ int hist[CBROWS];
  __shared__ int off[CBROWS];
  __shared__ int lcur[CBROWS];
  __shared__ int sbase;
  int b = blockIdx.x;
  int tid = threadIdx.x;
  int c = min(ccur[b], CAPC);
  if (tid < CBROWS) hist[tid] = 0;
  __syncthreads();
  const int4* p4 = (const int4*)(cstag + (size_t)b * CAPC);
  for (int i = tid; 2 * i < c; i += 512) {
    int4 q = p4[i];
    srec[2 * i] = make_int2(q.x, q.y);
    atomicAdd(&hist[(q.x >> 18) & (CBROWS - 1)], 1);
    if (2 * i + 1 < c) {
      srec[2 * i + 1] = make_int2(q.z, q.w);
      atomicAdd(&hist[(q.z >> 18) & (CBROWS - 1)], 1);
    }
  }
  __syncthreads();
  // exclusive scan of 256 EVEN-ALIGNED counters by wave 0
  // (lane l owns slots 4l..4l+3); lane 63 reserves the bin's global range.
  if (tid < 64) {
    int h0 = hist[4 * tid], h1 = hist[4 * tid + 1];
    int h2 = hist[4 * tid + 2], h3 = hist[4 * tid + 3];
    int a0 = (h0 + 1) & ~1, a1 = (h1 + 1) & ~1;
    int a2 = (h2 + 1) & ~1, a3 = (h3 + 1) & ~1;
    int s = a0 + a1 + a2 + a3;
    int incl = wave_iscan(s, tid);
    int e0 = incl - s;
    off[4 * tid] = e0;
    off[4 * tid + 1] = e0 + a0;
    off[4 * tid + 2] = e0 + a0 + a1;
    off[4 * tid + 3] = e0 + a0 + a1 + a2;
    if (tid == 63) sbase = atomicAdd(gcur, incl);  // incl = even total
  }
  __syncthreads();
  if (tid < CBROWS) lcur[tid] = off[tid];
  __syncthreads();
  int base = sbase;
  for (int i = tid; i < c; i += 512) {
    int2 r = srec[i];
    int ro = (r.x >> 18) & (CBROWS - 1);
    int pos = atomicAdd(&lcur[ro], 1);
    erec[base + pos] = make_int2(r.x & COLMASK, r.y);
  }
  int row = (b << CSH) + tid;
  if (tid < CBROWS && row < n_nodes) {
    int s0 = base + off[tid];
    ptr2[row] = make_int2(s0, s0 + hist[tid]);
  }
}

// Pull-SpMM: one wave per row; lane = slot(0..7) x choct(0..7).
// Slot s owns edges j+4s..j+4s+3 (records = 32B contiguous: 2 x int4).
// Fast path (whole slot valid): 4 x int4 gathers back-to-back + 32 fma_mix
// (full MLP). Slots entirely past row end issue ZERO gather requests; the
// single boundary slot takes a per-edge guarded path. 8 fp32 accumulators;
// 3-level shfl_xor reduction over slots. FIN: epilogue fuses (h1+h2+sum)/3
// and writes fp32 output directly. Blocks XCD-swizzled (bijective).
template <bool FIN>
__global__ __launch_bounds__(256) void k_spmm(
    const __half* __restrict__ cur, __half* __restrict__ nxt,
    const __half* __restrict__ h1, const __half* __restrict__ h2,
    float* __restrict__ out, const int2* __restrict__ ptr2,
    const int2* __restrict__ erec, int n, float scale) {
  // bijective XCD swizzle (m204 form): contiguous block ranges per XCD.
  int nwg = gridDim.x;
  int q = nwg >> 3, rr = nwg & 7;
  int xcd = blockIdx.x & 7, idx = blockIdx.x >> 3;
  int swz = (xcd < rr ? xcd * (q + 1) : rr * (q + 1) + (xcd - rr) * q) + idx;
  int w = (swz * 256 + threadIdx.x) >> 6;
  int lane = threadIdx.x & 63;
  if (w >= n) return;
  int2 se = ptr2[w];
  int start = se.x, end = se.y;
  int sub = lane >> 3;        // edge slot 0..7
  int ch = (lane & 7) << 3;   // half-offset within the 64-wide row (16B)
  float c0 = 0.f, c1 = 0.f, c2 = 0.f, c3 = 0.f;
  float c4 = 0.f, c5 = 0.f, c6 = 0.f, c7 = 0.f;
  const int2* eb = erec + 4 * sub;
  for (int j = start; j < end; j += 32) {
    // slot's 4 records, 32B contiguous, 16B-aligned (start even).
    int4 ra = *(const int4*)(eb + j);
    int4 rb = *(const int4*)(eb + j + 2);
    int e0 = j + 4 * sub;
    if (e0 + 3 < end) {
      // fast path: whole slot valid -- 4 gathers in flight, then 32 fma.
      int4 g0 = *(const int4*)(cur + (((ra.x & COLMASK) << 6) + ch));
      int4 g1 = *(const int4*)(cur + (((ra.z & COLMASK) << 6) + ch));
      int4 g2 = *(const int4*)(cur + (((rb.x & COLMASK) << 6) + ch));
      int4 g3 = *(const int4*)(cur + (((rb.z & COLMASK) << 6) + ch));
      float v0 = __int_as_float(ra.y), v1 = __int_as_float(ra.w);
      float v2 = __int_as_float(rb.y), v3 = __int_as_float(rb.w);
      FMA8(g0, v0);
      FMA8(g1, v1);
      FMA8(g2, v2);
      FMA8(g3, v3);
    } else {
      // boundary/empty slot: per-edge guarded (edge 3 invalid by branch).
      if (e0 + 0 < end) {
        int4 g = *(const int4*)(cur + (((ra.x & COLMASK) << 6) + ch));
        float v = __int_as_float(ra.y);
        FMA8(g, v);
      }
      if (e0 + 1 < end) {
        int4 g = *(const int4*)(cur + (((ra.z & COLMASK) << 6) + ch));
        float v = __int_as_float(ra.w);
        FMA8(g, v);
      }
      if (e0 + 2 < end) {
        int4 g = *(const int4*)(cur + (((rb.x & COLMASK) << 6) + ch));
        float v = __int_as_float(rb.y);
        FMA8(g, v);
      }
    }
  }
  // reduce across the 8 slots (lanes with same ch).
  c0 += __shfl_xor(c0, 8, 64); c0 += __shfl_xor(c0, 16, 64); c0 += __shfl_xor(c0, 32, 64);
  c1 += __shfl_xor(c1, 8, 64); c1 += __shfl_xor(c1, 16, 64); c1 += __shfl_xor(c1, 32, 64);
  c2 += __shfl_xor(c2, 8, 64); c2 += __shfl_xor(c2, 16, 64); c2 += __shfl_xor(c2, 32, 64);
  c3 += __shfl_xor(c3, 8, 64); c3 += __shfl_xor(c3, 16, 64); c3 += __shfl_xor(c3, 32, 64);
  c4 += __shfl_xor(c4, 8, 64); c4 += __shfl_xor(c4, 16, 64); c4 += __shfl_xor(c4, 32, 64);
  c5 += __shfl_xor(c5, 8, 64); c5 += __shfl_xor(c5, 16, 64); c5 += __shfl_xor(c5, 32, 64);
  c6 += __shfl_xor(c6, 8, 64); c6 += __shfl_xor(c6, 16, 64); c6 += __shfl_xor(c6, 32, 64);
  c7 += __shfl_xor(c7, 8, 64); c7 += __shfl_xor(c7, 16, 64); c7 += __shfl_xor(c7, 32, 64);
  if (sub == 0) {
    size_t o = ((size_t)w << 6) + ch;
    if (!FIN) {
      __half2 p0 = __halves2half2(__float2half(c0), __float2half(c1));
      __half2 p1 = __halves2half2(__float2half(c2), __float2half(c3));
      __half2 p2 = __halves2half2(__float2half(c4), __float2half(c5));
      __half2 p3 = __halves2half2(__float2half(c6), __float2half(c7));
      int4 pk;
      pk.x = *reinterpret_cast<int*>(&p0);
      pk.y = *reinterpret_cast<int*>(&p1);
      pk.z = *reinterpret_cast<int*>(&p2);
      pk.w = *reinterpret_cast<int*>(&p3);
      *reinterpret_cast<int4*>(nxt + o) = pk;
    } else {
      int4 x1 = *(const int4*)(h1 + o);
      int4 x2 = *(const int4*)(h2 + o);
      float2 u10 = __half22float2(*reinterpret_cast<__half2*>(&x1.x));
      float2 u11 = __half22float2(*reinterpret_cast<__half2*>(&x1.y));
      float2 u12 = __half22float2(*reinterpret_cast<__half2*>(&x1.z));
      float2 u13 = __half22float2(*reinterpret_cast<__half2*>(&x1.w));
      float2 u20 = __half22float2(*reinterpret_cast<__half2*>(&x2.x));
      float2 u21 = __half22float2(*reinterpret_cast<__half2*>(&x2.y));
      float2 u22 = __half22float2(*reinterpret_cast<__half2*>(&x2.z));
      float2 u23 = __half22float2(*reinterpret_cast<__half2*>(&x2.w));
      float4 r0, r1;
      r0.x = (u10.x + u20.x + c0) * scale;
      r0.y = (u10.y + u20.y + c1) * scale;
      r0.z = (u11.x + u21.x + c2) * scale;
      r0.w = (u11.y + u21.y + c3) * scale;
      r1.x = (u12.x + u22.x + c4) * scale;
      r1.y = (u12.y + u22.y + c5) * scale;
      r1.z = (u13.x + u23.x + c6) * scale;
      r1.w = (u13.y + u23.y + c7) * scale;
      *reinterpret_cast<float4*>(out + o) = r0;
      *reinterpret_cast<float4*>(out + o + 4) = r1;
    }
  }
}

extern "C" void kernel_launch(void* const* d_in, const int* in_sizes, int n_in,
                              void* d_out, int out_size, void* d_ws,
                              size_t ws_size, hipStream_t stream) {
  const float* ue = (const float*)d_in[0];
  const float* ie = (const float*)d_in[1];
  const float* vals = (const float*)d_in[2];
  const int* rows = (const int*)d_in[3];
  const int* cols = (const int*)d_in[4];

  const int EMB = 64;
  const int n_users = in_sizes[0] / EMB;
  const int n_items = in_sizes[1] / EMB;
  const int n_nodes = n_users + n_items;
  const int E = in_sizes[2];
  const int total_e = n_nodes * EMB;
  const int NC = (n_nodes + CBROWS - 1) >> CSH;  // coarse bins (<=1024)

  // Workspace layout (~152 MB). erec is padded: up to +1 record per row
  // (even alignment) plus 64 slack for spmm's unguarded record reads
  // (cstag follows -- always allocated).
  __half* h0 = (__half*)d_ws;           // ego
  __half* h1 = h0 + total_e;
  __half* h2 = h1 + total_e;
  int2* erec = (int2*)(h2 + total_e);   // final CSR records [E+n_nodes+64]
  int2* cstag = erec + E + n_nodes + 64;  // coarse staging [NC*CAPC]
  int* ccur = (int*)(cstag + (size_t)NC * CAPC);  // cursors [NC] + gcur [1]
  int* gcur = ccur + NC;
  int2* ptr2 = (int2*)(gcur + 8);       // per-row (start,end) [n_nodes]

  const int gP1 = (E + T1 - 1) / T1;
  const int gSpmm = (n_nodes + 3) / 4;

  // --- build ---
  hipMemsetAsync(ccur, 0, (NC + 1) * sizeof(int), stream);
  k_part1<<<gP1, 512, 0, stream>>>(rows, cols, vals, ccur, cstag, E, ue, ie,
                                   h0, n_users * EMB, total_e);
  k_csr<<<NC, 512, 0, stream>>>(cstag, ccur, gcur, erec, ptr2, n_nodes);

  // --- propagation; layer 3 fuses the mean + fp32 output write ---
  k_spmm<false><<<gSpmm, 256, 0, stream>>>(h0, h1, nullptr, nullptr, nullptr,
                                           ptr2, erec, n_nodes, 0.f);
  k_spmm<false><<<gSpmm, 256, 0, stream>>>(h1, h2, nullptr, nullptr, nullptr,
                                           ptr2, erec, n_nodes, 0.f);
  k_spmm<true><<<gSpmm, 256, 0, stream>>>(h2, nullptr, h1, h2, (float*)d_out,
                                          ptr2, erec, n_nodes, 1.0f / 3.0f);
}

// Round 7
// 463.430 us; speedup vs baseline: 1.0712x; 1.0712x over previous
//
#include <hip/hip_runtime.h>
#include <hip/hip_fp16.h>

// DimCL encoder, R13.
//  - spmm: R11's branchless masked-gather loop (the proven 95.7us form)
//    with R12's consecutive-slot mapping + 2 x int4 record loads (segments
//    even-aligned). NO divergent fast/slow branch (R12's regression).
//  - k_part1: LDS diet -- offs/gbase merged into cnt[] as a direct
//    write-index base (b*CAPC + gbase - offs). 52->48KB LDS => 3 blocks/CU
//    (24 waves/CU vs 16), one fewer barrier.
//  - k_csr: R12 even-padding version unchanged.
// Layers fp16, all math fp32.

#define CSH 8             // 256 rows per coarse bin
#define CBROWS (1 << CSH)
#define CAPC 6144         // bin capacity (avg ~5120, ~14 sigma slack)
#define T1 4096           // edges per k_part1 block tile
#define EPT 8             // edges per thread in k_part1 (T1 = 512*EPT)
#define COLMASK 0x3FFFF   // n_nodes < 2^18

// acc += (float)lo_half(pk) * v   /   acc += (float)hi_half(pk) * v
#define FMAMIX_LO(acc, pk, v)                                             \
  asm("v_fma_mix_f32 %0, %1, %2, %0 op_sel:[0,0,0] op_sel_hi:[1,0,0]"     \
      : "+v"(acc)                                                         \
      : "v"(pk), "v"(v))
#define FMAMIX_HI(acc, pk, v)                                             \
  asm("v_fma_mix_f32 %0, %1, %2, %0 op_sel:[1,0,0] op_sel_hi:[1,0,0]"     \
      : "+v"(acc)                                                         \
      : "v"(pk), "v"(v))

#define FMA8(g, v)                                                        \
  do {                                                                    \
    FMAMIX_LO(c0, (g).x, (v)); FMAMIX_HI(c1, (g).x, (v));                 \
    FMAMIX_LO(c2, (g).y, (v)); FMAMIX_HI(c3, (g).y, (v));                 \
    FMAMIX_LO(c4, (g).z, (v)); FMAMIX_HI(c5, (g).z, (v));                 \
    FMAMIX_LO(c6, (g).w, (v)); FMAMIX_HI(c7, (g).w, (v));                 \
  } while (0)

__device__ __forceinline__ int wave_iscan(int v, int lane) {
#pragma unroll
  for (int off = 1; off < 64; off <<= 1) {
    int t = __shfl_up(v, off, 64);
    if (lane >= off) v += t;
  }
  return v;
}

// Coarse multi-split, 512 threads: fused ego convert, then per-block LDS
// histogram + scan + reserve + reorder, bin-sorted copy-out to staging.
// LDS 48KB -> 3 blocks/CU. Requires NC <= 1024 (n_nodes <= 262144).
__global__ __launch_bounds__(512) void k_part1(
    const int* __restrict__ rows, const int* __restrict__ cols,
    const float* __restrict__ vals, int* __restrict__ ccur,
    int2* __restrict__ cstag, int E,
    const float* __restrict__ ue, const float* __restrict__ ie,
    __half* __restrict__ h0, int nuser_e, int total_e) {
  __shared__ int cnt[1024];   // counts; after reserve: cstag write-idx base
  __shared__ int lcur[1024];
  __shared__ int wsum8[8];
  __shared__ int2 sout[T1];
  __shared__ unsigned short sbin[T1];
  int tid = threadIdx.x;
  int lane = tid & 63, wid = tid >> 6;
  int base = blockIdx.x * T1;

  // fused ego init (streaming; overlaps other blocks' latency phases)
  for (int i = blockIdx.x * 512 + tid; i < total_e; i += gridDim.x * 512) {
    float x = (i < nuser_e) ? ue[i] : ie[i - nuser_e];
    h0[i] = __float2half(x);
  }

  cnt[tid] = 0;
  cnt[tid + 512] = 0;
  __syncthreads();

  int recx[EPT], recy[EPT], rbin[EPT];
#pragma unroll
  for (int k = 0; k < EPT; ++k) {
    int idx = base + k * 512 + tid;
    if (idx < E) {
      int r = rows[idx];
      int b = r >> CSH;
      recx[k] = cols[idx] | ((r & (CBROWS - 1)) << 18);
      recy[k] = __float_as_int(vals[idx]);
      rbin[k] = b;
      atomicAdd(&cnt[b], 1);
    } else {
      rbin[k] = -1;
    }
  }
  __syncthreads();

  // exclusive scan of 1024 counters: thread t owns slots 2t, 2t+1.
  int t0 = 2 * tid, t1 = 2 * tid + 1;
  int c0 = cnt[t0], c1 = cnt[t1];
  int s = c0 + c1;
  int incl = wave_iscan(s, lane);
  if (lane == 63) wsum8[wid] = incl;
  __syncthreads();
  if (wid == 0) {
    int t = (lane < 8) ? wsum8[lane] : 0;
    t = wave_iscan(t, lane);
    if (lane < 8) wsum8[lane] = t;
  }
  __syncthreads();
  int woff = wid ? wsum8[wid - 1] : 0;
  incl += woff;
  int e0 = incl - s;
  lcur[t0] = e0;
  lcur[t1] = e0 + c0;
  // reserve global range per bin; cnt[b] becomes the direct cstag write
  // index base: b*CAPC + gbase - offs_b (owner thread read+write: no hazard)
  int g0 = (c0 > 0) ? atomicAdd(&ccur[t0], c0) : 0;
  int g1 = (c1 > 0) ? atomicAdd(&ccur[t1], c1) : 0;
  cnt[t0] = t0 * CAPC + g0 - e0;
  cnt[t1] = t1 * CAPC + g1 - (e0 + c0);
  __syncthreads();

  // bin-sorted reorder into LDS.
#pragma unroll
  for (int k = 0; k < EPT; ++k) {
    if (rbin[k] >= 0) {
      int p = atomicAdd(&lcur[rbin[k]], 1);
      sout[p] = make_int2(recx[k], recy[k]);
      sbin[p] = (unsigned short)rbin[k];
    }
  }
  __syncthreads();

  // run-coalesced copy-out: consecutive i -> same bin -> consecutive addrs.
  int m = min(T1, E - base);
  for (int i = tid; i < m; i += 512) {
    int b = sbin[i];
    int idx = cnt[b] + i;                 // absolute cstag index
    if (idx < (b + 1) * CAPC) cstag[idx] = sout[i];
  }
}

// Fused CSR finalize: one block per bin. Bin base from a global atomic
// cursor. Row counts rounded UP TO EVEN in the scan so every row segment
// starts at an even record index (16B alignment for spmm's int4 record
// loads); pad slots are never referenced as valid. Stage records in LDS
// (int4 = 2 records per load), per-row hist, in-block scan, scatter to
// final erec (bin's contiguous ~40KB chunk, L2-resident), write per-row
// (start,end) int2.
__global__ __launch_bounds__(512) void k_csr(
    const int2* __restrict__ cstag, const int* __restrict__ ccur,
    int* __restrict__ gcur, int2* __restrict__ erec,
    int2* __restrict__ ptr2, int n_nodes) {
  __shared__ int2 srec[CAPC];     // 48KB
  __shared__ int hist[CBROWS];
  __shared__ int off[CBROWS];
  __shared__ int lcur[CBROWS];
  __shared__ int sbase;
  int b = blockIdx.x;
  int tid = threadIdx.x;
  int c = min(ccur[b], CAPC);
  if (tid < CBROWS) hist[tid] = 0;
  __syncthreads();
  const int4* p4 = (const int4*)(cstag + (size_t)b * CAPC);
  for (int i = tid; 2 * i < c; i += 512) {
    int4 q = p4[i];
    srec[2 * i] = make_int2(q.x, q.y);
    atomicAdd(&hist[(q.x >> 18) & (CBROWS - 1)], 1);
    if (2 * i + 1 < c) {
      srec[2 * i + 1] = make_int2(q.z, q.w);
      atomicAdd(&hist[(q.z >> 18) & (CBROWS - 1)], 1);
    }
  }
  __syncthreads();
  // exclusive scan of 256 EVEN-ALIGNED counters by wave 0
  // (lane l owns slots 4l..4l+3); lane 63 reserves the bin's global range.
  if (tid < 64) {
    int h0 = hist[4 * tid], h1 = hist[4 * tid + 1];
    int h2 = hist[4 * tid + 2], h3 = hist[4 * tid + 3];
    int a0 = (h0 + 1) & ~1, a1 = (h1 + 1) & ~1;
    int a2 = (h2 + 1) & ~1, a3 = (h3 + 1) & ~1;
    int s = a0 + a1 + a2 + a3;
    int incl = wave_iscan(s, tid);
    int e0 = incl - s;
    off[4 * tid] = e0;
    off[4 * tid + 1] = e0 + a0;
    off[4 * tid + 2] = e0 + a0 + a1;
    off[4 * tid + 3] = e0 + a0 + a1 + a2;
    if (tid == 63) sbase = atomicAdd(gcur, incl);  // incl = even total
  }
  __syncthreads();
  if (tid < CBROWS) lcur[tid] = off[tid];
  __syncthreads();
  int base = sbase;
  for (int i = tid; i < c; i += 512) {
    int2 r = srec[i];
    int ro = (r.x >> 18) & (CBROWS - 1);
    int pos = atomicAdd(&lcur[ro], 1);
    erec[base + pos] = make_int2(r.x & COLMASK, r.y);
  }
  int row = (b << CSH) + tid;
  if (tid < CBROWS && row < n_nodes) {
    int s0 = base + off[tid];
    ptr2[row] = make_int2(s0, s0 + hist[tid]);
  }
}

// Pull-SpMM: one wave per row; lane = slot(0..7) x choct(0..7).
// Slot s owns edges j+4s..j+4s+3 (records 32B contiguous: 2 x int4,
// segments even-aligned). BRANCHLESS: phantom slots' gather offsets masked
// to row 0 (L1-hot), values zeroed -- uniform control flow, 4 gathers in
// flight per lane. 8 fp32 accumulators; 3-level shfl_xor reduction.
// FIN: epilogue fuses (h1+h2+sum)/3, writes fp32 output directly.
// Blocks XCD-swizzled (bijective).
template <bool FIN>
__global__ __launch_bounds__(256) void k_spmm(
    const __half* __restrict__ cur, __half* __restrict__ nxt,
    const __half* __restrict__ h1, const __half* __restrict__ h2,
    float* __restrict__ out, const int2* __restrict__ ptr2,
    const int2* __restrict__ erec, int n, float scale) {
  // bijective XCD swizzle (m204 form): contiguous block ranges per XCD.
  int nwg = gridDim.x;
  int q = nwg >> 3, rr = nwg & 7;
  int xcd = blockIdx.x & 7, idx = blockIdx.x >> 3;
  int swz = (xcd < rr ? xcd * (q + 1) : rr * (q + 1) + (xcd - rr) * q) + idx;
  int w = (swz * 256 + threadIdx.x) >> 6;
  int lane = threadIdx.x & 63;
  if (w >= n) return;
  int2 se = ptr2[w];
  int start = se.x, end = se.y;
  int sub = lane >> 3;        // edge slot 0..7
  int ch = (lane & 7) << 3;   // half-offset within the 64-wide row (16B)
  float c0 = 0.f, c1 = 0.f, c2 = 0.f, c3 = 0.f;
  float c4 = 0.f, c5 = 0.f, c6 = 0.f, c7 = 0.f;
  const int2* eb = erec + 4 * sub;
  for (int j = start; j < end; j += 32) {
    // slot's 4 records, 32B contiguous, 16B-aligned (start even).
    int4 ra = *(const int4*)(eb + j);
    int4 rb = *(const int4*)(eb + j + 2);
    int e0 = j + 4 * sub;
    bool k0 = e0 < end, k1 = e0 + 1 < end;
    bool k2 = e0 + 2 < end, k3 = e0 + 3 < end;
    int o0 = k0 ? (((ra.x & COLMASK) << 6) + ch) : ch;
    int o1 = k1 ? (((ra.z & COLMASK) << 6) + ch) : ch;
    int o2 = k2 ? (((rb.x & COLMASK) << 6) + ch) : ch;
    int o3 = k3 ? (((rb.z & COLMASK) << 6) + ch) : ch;
    float v0 = k0 ? __int_as_float(ra.y) : 0.f;
    float v1 = k1 ? __int_as_float(ra.w) : 0.f;
    float v2 = k2 ? __int_as_float(rb.y) : 0.f;
    float v3 = k3 ? __int_as_float(rb.w) : 0.f;
    int4 g0 = *(const int4*)(cur + o0);
    int4 g1 = *(const int4*)(cur + o1);
    int4 g2 = *(const int4*)(cur + o2);
    int4 g3 = *(const int4*)(cur + o3);
    FMA8(g0, v0);
    FMA8(g1, v1);
    FMA8(g2, v2);
    FMA8(g3, v3);
  }
  // reduce across the 8 slots (lanes with same ch).
  c0 += __shfl_xor(c0, 8, 64); c0 += __shfl_xor(c0, 16, 64); c0 += __shfl_xor(c0, 32, 64);
  c1 += __shfl_xor(c1, 8, 64); c1 += __shfl_xor(c1, 16, 64); c1 += __shfl_xor(c1, 32, 64);
  c2 += __shfl_xor(c2, 8, 64); c2 += __shfl_xor(c2, 16, 64); c2 += __shfl_xor(c2, 32, 64);
  c3 += __shfl_xor(c3, 8, 64); c3 += __shfl_xor(c3, 16, 64); c3 += __shfl_xor(c3, 32, 64);
  c4 += __shfl_xor(c4, 8, 64); c4 += __shfl_xor(c4, 16, 64); c4 += __shfl_xor(c4, 32, 64);
  c5 += __shfl_xor(c5, 8, 64); c5 += __shfl_xor(c5, 16, 64); c5 += __shfl_xor(c5, 32, 64);
  c6 += __shfl_xor(c6, 8, 64); c6 += __shfl_xor(c6, 16, 64); c6 += __shfl_xor(c6, 32, 64);
  c7 += __shfl_xor(c7, 8, 64); c7 += __shfl_xor(c7, 16, 64); c7 += __shfl_xor(c7, 32, 64);
  if (sub == 0) {
    size_t o = ((size_t)w << 6) + ch;
    if (!FIN) {
      __half2 p0 = __halves2half2(__float2half(c0), __float2half(c1));
      __half2 p1 = __halves2half2(__float2half(c2), __float2half(c3));
      __half2 p2 = __halves2half2(__float2half(c4), __float2half(c5));
      __half2 p3 = __halves2half2(__float2half(c6), __float2half(c7));
      int4 pk;
      pk.x = *reinterpret_cast<int*>(&p0);
      pk.y = *reinterpret_cast<int*>(&p1);
      pk.z = *reinterpret_cast<int*>(&p2);
      pk.w = *reinterpret_cast<int*>(&p3);
      *reinterpret_cast<int4*>(nxt + o) = pk;
    } else {
      int4 x1 = *(const int4*)(h1 + o);
      int4 x2 = *(const int4*)(h2 + o);
      float2 u10 = __half22float2(*reinterpret_cast<__half2*>(&x1.x));
      float2 u11 = __half22float2(*reinterpret_cast<__half2*>(&x1.y));
      float2 u12 = __half22float2(*reinterpret_cast<__half2*>(&x1.z));
      float2 u13 = __half22float2(*reinterpret_cast<__half2*>(&x1.w));
      float2 u20 = __half22float2(*reinterpret_cast<__half2*>(&x2.x));
      float2 u21 = __half22float2(*reinterpret_cast<__half2*>(&x2.y));
      float2 u22 = __half22float2(*reinterpret_cast<__half2*>(&x2.z));
      float2 u23 = __half22float2(*reinterpret_cast<__half2*>(&x2.w));
      float4 r0, r1;
      r0.x = (u10.x + u20.x + c0) * scale;
      r0.y = (u10.y + u20.y + c1) * scale;
      r0.z = (u11.x + u21.x + c2) * scale;
      r0.w = (u11.y + u21.y + c3) * scale;
      r1.x = (u12.x + u22.x + c4) * scale;
      r1.y = (u12.y + u22.y + c5) * scale;
      r1.z = (u13.x + u23.x + c6) * scale;
      r1.w = (u13.y + u23.y + c7) * scale;
      *reinterpret_cast<float4*>(out + o) = r0;
      *reinterpret_cast<float4*>(out + o + 4) = r1;
    }
  }
}

extern "C" void kernel_launch(void* const* d_in, const int* in_sizes, int n_in,
                              void* d_out, int out_size, void* d_ws,
                              size_t ws_size, hipStream_t stream) {
  const float* ue = (const float*)d_in[0];
  const float* ie = (const float*)d_in[1];
  const float* vals = (const float*)d_in[2];
  const int* rows = (const int*)d_in[3];
  const int* cols = (const int*)d_in[4];

  const int EMB = 64;
  const int n_users = in_sizes[0] / EMB;
  const int n_items = in_sizes[1] / EMB;
  const int n_nodes = n_users + n_items;
  const int E = in_sizes[2];
  const int total_e = n_nodes * EMB;
  const int NC = (n_nodes + CBROWS - 1) >> CSH;  // coarse bins (<=1024)

  // Workspace layout (~152 MB). erec is padded: up to +1 record per row
  // (even alignment) plus 64 slack for spmm's unguarded record reads
  // (cstag follows -- always allocated).
  __half* h0 = (__half*)d_ws;           // ego
  __half* h1 = h0 + total_e;
  __half* h2 = h1 + total_e;
  int2* erec = (int2*)(h2 + total_e);   // final CSR records [E+n_nodes+64]
  int2* cstag = erec + E + n_nodes + 64;  // coarse staging [NC*CAPC]
  int* ccur = (int*)(cstag + (size_t)NC * CAPC);  // cursors [NC] + gcur [1]
  int* gcur = ccur + NC;
  int2* ptr2 = (int2*)(gcur + 8);       // per-row (start,end) [n_nodes]

  const int gP1 = (E + T1 - 1) / T1;
  const int gSpmm = (n_nodes + 3) / 4;

  // --- build ---
  hipMemsetAsync(ccur, 0, (NC + 1) * sizeof(int), stream);
  k_part1<<<gP1, 512, 0, stream>>>(rows, cols, vals, ccur, cstag, E, ue, ie,
                                   h0, n_users * EMB, total_e);
  k_csr<<<NC, 512, 0, stream>>>(cstag, ccur, gcur, erec, ptr2, n_nodes);

  // --- propagation; layer 3 fuses the mean + fp32 output write ---
  k_spmm<false><<<gSpmm, 256, 0, stream>>>(h0, h1, nullptr, nullptr, nullptr,
                                           ptr2, erec, n_nodes, 0.f);
  k_spmm<false><<<gSpmm, 256, 0, stream>>>(h1, h2, nullptr, nullptr, nullptr,
                                           ptr2, erec, n_nodes, 0.f);
  k_spmm<true><<<gSpmm, 256, 0, stream>>>(h2, nullptr, h1, h2, (float*)d_out,
                                          ptr2, erec, n_nodes, 1.0f / 3.0f);
}

// Round 8
// 421.065 us; speedup vs baseline: 1.1790x; 1.1006x over previous
//
#include <hip/hip_runtime.h>
#include <hip/hip_fp16.h>

// DimCL encoder, R14.
//  - spmm: unchanged from R13 (branchless masked gather, 8 lanes x int4 per
//    row, consecutive-slot int4 record loads). At compulsory-fetch floor.
//  - k_part1: 1024 threads/block (EPT=4, same T1=4096 tile), LDS 48.5KB ->
//    2 blocks/CU = 32 waves/CU (100% occupancy, was 46%); edge loads
//    vectorized int4/float4 (12 scalar -> 3 vector requests/thread); fused
//    ego-init vectorized float4->half4.
//  - k_csr: 1024 threads (100% occupancy, was 75%).
// Layers fp16, all math fp32.

#define CSH 8             // 256 rows per coarse bin
#define CBROWS (1 << CSH)
#define CAPC 6144         // bin capacity (avg ~5120, ~14 sigma slack)
#define T1 4096           // edges per k_part1 block tile
#define EPT 4             // edges per thread in k_part1 (T1 = 1024*EPT)
#define COLMASK 0x3FFFF   // n_nodes < 2^18

// acc += (float)lo_half(pk) * v   /   acc += (float)hi_half(pk) * v
#define FMAMIX_LO(acc, pk, v)                                             \
  asm("v_fma_mix_f32 %0, %1, %2, %0 op_sel:[0,0,0] op_sel_hi:[1,0,0]"     \
      : "+v"(acc)                                                         \
      : "v"(pk), "v"(v))
#define FMAMIX_HI(acc, pk, v)                                             \
  asm("v_fma_mix_f32 %0, %1, %2, %0 op_sel:[1,0,0] op_sel_hi:[1,0,0]"     \
      : "+v"(acc)                                                         \
      : "v"(pk), "v"(v))

#define FMA8(g, v)                                                        \
  do {                                                                    \
    FMAMIX_LO(c0, (g).x, (v)); FMAMIX_HI(c1, (g).x, (v));                 \
    FMAMIX_LO(c2, (g).y, (v)); FMAMIX_HI(c3, (g).y, (v));                 \
    FMAMIX_LO(c4, (g).z, (v)); FMAMIX_HI(c5, (g).z, (v));                 \
    FMAMIX_LO(c6, (g).w, (v)); FMAMIX_HI(c7, (g).w, (v));                 \
  } while (0)

__device__ __forceinline__ int wave_iscan(int v, int lane) {
#pragma unroll
  for (int off = 1; off < 64; off <<= 1) {
    int t = __shfl_up(v, off, 64);
    if (lane >= off) v += t;
  }
  return v;
}

// Coarse multi-split, 1024 threads: fused ego convert (vectorized), then
// per-block LDS histogram + scan + reserve + reorder, bin-sorted copy-out.
// LDS 48.5KB, 1024 thr -> 2 blocks/CU = 32 waves/CU (100%).
// Requires NC <= 1024 (n_nodes <= 262144).
__global__ __launch_bounds__(1024) void k_part1(
    const int* __restrict__ rows, const int* __restrict__ cols,
    const float* __restrict__ vals, int* __restrict__ ccur,
    int2* __restrict__ cstag, int E,
    const float* __restrict__ ue, const float* __restrict__ ie,
    __half* __restrict__ h0, int nuser_e, int total_e) {
  __shared__ int cnt[1024];   // counts; after reserve: cstag write-idx base
  __shared__ int lcur[1024];
  __shared__ int wsum[16];
  __shared__ int2 sout[T1];
  __shared__ unsigned short sbin[T1];
  int tid = threadIdx.x;
  int lane = tid & 63, wid = tid >> 6;
  int base = blockIdx.x * T1;

  // fused ego init, vectorized: float4 in -> 4x half out (8B store).
  int nq = total_e >> 2;
  for (int i = blockIdx.x * 1024 + tid; i < nq; i += gridDim.x * 1024) {
    int e = i << 2;
    float4 x = (e + 3 < nuser_e)
                   ? *(const float4*)(ue + e)
                   : (e >= nuser_e)
                         ? *(const float4*)(ie + (e - nuser_e))
                         : make_float4(  // straddles user/item boundary
                               (e + 0 < nuser_e) ? ue[e + 0] : ie[e + 0 - nuser_e],
                               (e + 1 < nuser_e) ? ue[e + 1] : ie[e + 1 - nuser_e],
                               (e + 2 < nuser_e) ? ue[e + 2] : ie[e + 2 - nuser_e],
                               (e + 3 < nuser_e) ? ue[e + 3] : ie[e + 3 - nuser_e]);
    __half2 lo = __halves2half2(__float2half(x.x), __float2half(x.y));
    __half2 hi = __halves2half2(__float2half(x.z), __float2half(x.w));
    int2 pk;
    pk.x = *reinterpret_cast<int*>(&lo);
    pk.y = *reinterpret_cast<int*>(&hi);
    *reinterpret_cast<int2*>(h0 + e) = pk;
  }

  cnt[tid] = 0;
  __syncthreads();

  // blocked edge mapping: thread owns edges base+4*tid .. +3 (int4 loads).
  int i0 = base + 4 * tid;
  int rr[EPT], cc[EPT];
  float vv[EPT];
  if (i0 + 3 < E) {
    int4 r4 = *(const int4*)(rows + i0);
    int4 c4 = *(const int4*)(cols + i0);
    float4 v4 = *(const float4*)(vals + i0);
    rr[0] = r4.x; rr[1] = r4.y; rr[2] = r4.z; rr[3] = r4.w;
    cc[0] = c4.x; cc[1] = c4.y; cc[2] = c4.z; cc[3] = c4.w;
    vv[0] = v4.x; vv[1] = v4.y; vv[2] = v4.z; vv[3] = v4.w;
  } else {
#pragma unroll
    for (int k = 0; k < EPT; ++k) {
      int idx = i0 + k;
      rr[k] = (idx < E) ? rows[idx] : -1;
      cc[k] = (idx < E) ? cols[idx] : 0;
      vv[k] = (idx < E) ? vals[idx] : 0.f;
    }
  }
  int recx[EPT], rbin[EPT];
#pragma unroll
  for (int k = 0; k < EPT; ++k) {
    if (rr[k] >= 0) {
      int b = rr[k] >> CSH;
      recx[k] = cc[k] | ((rr[k] & (CBROWS - 1)) << 18);
      rbin[k] = b;
      atomicAdd(&cnt[b], 1);
    } else {
      rbin[k] = -1;
    }
  }
  __syncthreads();

  // exclusive scan of 1024 counters (1 per thread).
  int c0 = cnt[tid];
  int incl = wave_iscan(c0, lane);
  if (lane == 63) wsum[wid] = incl;
  __syncthreads();
  if (wid == 0) {
    int t = (lane < 16) ? wsum[lane] : 0;
    t = wave_iscan(t, lane);
    if (lane < 16) wsum[lane] = t;
  }
  __syncthreads();
  int woff = wid ? wsum[wid - 1] : 0;
  int e0 = incl + woff - c0;  // exclusive offset of bin tid
  lcur[tid] = e0;
  // reserve global range; cnt[tid] becomes direct cstag write-index base
  // (owner-thread read+write only: no hazard).
  int g = (c0 > 0) ? atomicAdd(&ccur[tid], c0) : 0;
  cnt[tid] = tid * CAPC + g - e0;
  __syncthreads();

  // bin-sorted reorder into LDS.
#pragma unroll
  for (int k = 0; k < EPT; ++k) {
    if (rbin[k] >= 0) {
      int p = atomicAdd(&lcur[rbin[k]], 1);
      sout[p] = make_int2(recx[k], __float_as_int(vv[k]));
      sbin[p] = (unsigned short)rbin[k];
    }
  }
  __syncthreads();

  // run-coalesced copy-out: consecutive i -> same bin -> consecutive addrs.
  int m = min(T1, E - base);
  for (int i = tid; i < m; i += 1024) {
    int b = sbin[i];
    int idx = cnt[b] + i;                 // absolute cstag index
    if (idx < (b + 1) * CAPC) cstag[idx] = sout[i];
  }
}

// Fused CSR finalize: one block per bin, 1024 threads (2 blocks/CU, 100%
// occupancy). Bin base from a global atomic cursor. Row counts rounded UP
// TO EVEN so every row segment starts at an even record index (16B-aligned
// int4 record loads in spmm); pads never referenced as valid. Stage records
// in LDS (int4 = 2 records/load), per-row hist, in-block scan, scatter to
// erec (bin's contiguous ~40KB chunk, L2-resident), write per-row
// (start,end) int2.
__global__ __launch_bounds__(1024) void k_csr(
    const int2* __restrict__ cstag, const int* __restrict__ ccur,
    int* __restrict__ gcur, int2* __restrict__ erec,
    int2* __restrict__ ptr2, int n_nodes) {
  __shared__ int2 srec[CAPC];     // 48KB
  __shared__ int hist[CBROWS];
  __shared__ int off[CBROWS];
  __shared__ int lcur[CBROWS];
  __shared__ int sbase;
  int b = blockIdx.x;
  int tid = threadIdx.x;
  int c = min(ccur[b], CAPC);
  if (tid < CBROWS) hist[tid] = 0;
  __syncthreads();
  const int4* p4 = (const int4*)(cstag + (size_t)b * CAPC);
  for (int i = tid; 2 * i < c; i += 1024) {
    int4 q = p4[i];
    srec[2 * i] = make_int2(q.x, q.y);
    atomicAdd(&hist[(q.x >> 18) & (CBROWS - 1)], 1);
    if (2 * i + 1 < c) {
      srec[2 * i + 1] = make_int2(q.z, q.w);
      atomicAdd(&hist[(q.z >> 18) & (CBROWS - 1)], 1);
    }
  }
  __syncthreads();
  // exclusive scan of 256 EVEN-ALIGNED counters by wave 0
  // (lane l owns slots 4l..4l+3); lane 63 reserves the bin's global range.
  if (tid < 64) {
    int h0 = hist[4 * tid], h1 = hist[4 * tid + 1];
    int h2 = hist[4 * tid + 2], h3 = hist[4 * tid + 3];
    int a0 = (h0 + 1) & ~1, a1 = (h1 + 1) & ~1;
    int a2 = (h2 + 1) & ~1, a3 = (h3 + 1) & ~1;
    int s = a0 + a1 + a2 + a3;
    int incl = wave_iscan(s, tid);
    int e0 = incl - s;
    off[4 * tid] = e0;
    off[4 * tid + 1] = e0 + a0;
    off[4 * tid + 2] = e0 + a0 + a1;
    off[4 * tid + 3] = e0 + a0 + a1 + a2;
    if (tid == 63) sbase = atomicAdd(gcur, incl);  // incl = even total
  }
  __syncthreads();
  if (tid < CBROWS) lcur[tid] = off[tid];
  __syncthreads();
  int base = sbase;
  for (int i = tid; i < c; i += 1024) {
    int2 r = srec[i];
    int ro = (r.x >> 18) & (CBROWS - 1);
    int pos = atomicAdd(&lcur[ro], 1);
    erec[base + pos] = make_int2(r.x & COLMASK, r.y);
  }
  int row = (b << CSH) + tid;
  if (tid < CBROWS && row < n_nodes) {
    int s0 = base + off[tid];
    ptr2[row] = make_int2(s0, s0 + hist[tid]);
  }
}

// Pull-SpMM: one wave per row; lane = slot(0..7) x choct(0..7).
// Slot s owns edges j+4s..j+4s+3 (records 32B contiguous: 2 x int4,
// segments even-aligned). BRANCHLESS: phantom slots' gather offsets masked
// to row 0 (L1-hot), values zeroed -- uniform control flow, 4 gathers in
// flight per lane. 8 fp32 accumulators; 3-level shfl_xor reduction.
// FIN: epilogue fuses (h1+h2+sum)/3, writes fp32 output directly.
// Blocks XCD-swizzled (bijective).
template <bool FIN>
__global__ __launch_bounds__(256) void k_spmm(
    const __half* __restrict__ cur, __half* __restrict__ nxt,
    const __half* __restrict__ h1, const __half* __restrict__ h2,
    float* __restrict__ out, const int2* __restrict__ ptr2,
    const int2* __restrict__ erec, int n, float scale) {
  // bijective XCD swizzle (m204 form): contiguous block ranges per XCD.
  int nwg = gridDim.x;
  int q = nwg >> 3, rr = nwg & 7;
  int xcd = blockIdx.x & 7, idx = blockIdx.x >> 3;
  int swz = (xcd < rr ? xcd * (q + 1) : rr * (q + 1) + (xcd - rr) * q) + idx;
  int w = (swz * 256 + threadIdx.x) >> 6;
  int lane = threadIdx.x & 63;
  if (w >= n) return;
  int2 se = ptr2[w];
  int start = se.x, end = se.y;
  int sub = lane >> 3;        // edge slot 0..7
  int ch = (lane & 7) << 3;   // half-offset within the 64-wide row (16B)
  float c0 = 0.f, c1 = 0.f, c2 = 0.f, c3 = 0.f;
  float c4 = 0.f, c5 = 0.f, c6 = 0.f, c7 = 0.f;
  const int2* eb = erec + 4 * sub;
  for (int j = start; j < end; j += 32) {
    // slot's 4 records, 32B contiguous, 16B-aligned (start even).
    int4 ra = *(const int4*)(eb + j);
    int4 rb = *(const int4*)(eb + j + 2);
    int e0 = j + 4 * sub;
    bool k0 = e0 < end, k1 = e0 + 1 < end;
    bool k2 = e0 + 2 < end, k3 = e0 + 3 < end;
    int o0 = k0 ? (((ra.x & COLMASK) << 6) + ch) : ch;
    int o1 = k1 ? (((ra.z & COLMASK) << 6) + ch) : ch;
    int o2 = k2 ? (((rb.x & COLMASK) << 6) + ch) : ch;
    int o3 = k3 ? (((rb.z & COLMASK) << 6) + ch) : ch;
    float v0 = k0 ? __int_as_float(ra.y) : 0.f;
    float v1 = k1 ? __int_as_float(ra.w) : 0.f;
    float v2 = k2 ? __int_as_float(rb.y) : 0.f;
    float v3 = k3 ? __int_as_float(rb.w) : 0.f;
    int4 g0 = *(const int4*)(cur + o0);
    int4 g1 = *(const int4*)(cur + o1);
    int4 g2 = *(const int4*)(cur + o2);
    int4 g3 = *(const int4*)(cur + o3);
    FMA8(g0, v0);
    FMA8(g1, v1);
    FMA8(g2, v2);
    FMA8(g3, v3);
  }
  // reduce across the 8 slots (lanes with same ch).
  c0 += __shfl_xor(c0, 8, 64); c0 += __shfl_xor(c0, 16, 64); c0 += __shfl_xor(c0, 32, 64);
  c1 += __shfl_xor(c1, 8, 64); c1 += __shfl_xor(c1, 16, 64); c1 += __shfl_xor(c1, 32, 64);
  c2 += __shfl_xor(c2, 8, 64); c2 += __shfl_xor(c2, 16, 64); c2 += __shfl_xor(c2, 32, 64);
  c3 += __shfl_xor(c3, 8, 64); c3 += __shfl_xor(c3, 16, 64); c3 += __shfl_xor(c3, 32, 64);
  c4 += __shfl_xor(c4, 8, 64); c4 += __shfl_xor(c4, 16, 64); c4 += __shfl_xor(c4, 32, 64);
  c5 += __shfl_xor(c5, 8, 64); c5 += __shfl_xor(c5, 16, 64); c5 += __shfl_xor(c5, 32, 64);
  c6 += __shfl_xor(c6, 8, 64); c6 += __shfl_xor(c6, 16, 64); c6 += __shfl_xor(c6, 32, 64);
  c7 += __shfl_xor(c7, 8, 64); c7 += __shfl_xor(c7, 16, 64); c7 += __shfl_xor(c7, 32, 64);
  if (sub == 0) {
    size_t o = ((size_t)w << 6) + ch;
    if (!FIN) {
      __half2 p0 = __halves2half2(__float2half(c0), __float2half(c1));
      __half2 p1 = __halves2half2(__float2half(c2), __float2half(c3));
      __half2 p2 = __halves2half2(__float2half(c4), __float2half(c5));
      __half2 p3 = __halves2half2(__float2half(c6), __float2half(c7));
      int4 pk;
      pk.x = *reinterpret_cast<int*>(&p0);
      pk.y = *reinterpret_cast<int*>(&p1);
      pk.z = *reinterpret_cast<int*>(&p2);
      pk.w = *reinterpret_cast<int*>(&p3);
      *reinterpret_cast<int4*>(nxt + o) = pk;
    } else {
      int4 x1 = *(const int4*)(h1 + o);
      int4 x2 = *(const int4*)(h2 + o);
      float2 u10 = __half22float2(*reinterpret_cast<__half2*>(&x1.x));
      float2 u11 = __half22float2(*reinterpret_cast<__half2*>(&x1.y));
      float2 u12 = __half22float2(*reinterpret_cast<__half2*>(&x1.z));
      float2 u13 = __half22float2(*reinterpret_cast<__half2*>(&x1.w));
      float2 u20 = __half22float2(*reinterpret_cast<__half2*>(&x2.x));
      float2 u21 = __half22float2(*reinterpret_cast<__half2*>(&x2.y));
      float2 u22 = __half22float2(*reinterpret_cast<__half2*>(&x2.z));
      float2 u23 = __half22float2(*reinterpret_cast<__half2*>(&x2.w));
      float4 r0, r1;
      r0.x = (u10.x + u20.x + c0) * scale;
      r0.y = (u10.y + u20.y + c1) * scale;
      r0.z = (u11.x + u21.x + c2) * scale;
      r0.w = (u11.y + u21.y + c3) * scale;
      r1.x = (u12.x + u22.x + c4) * scale;
      r1.y = (u12.y + u22.y + c5) * scale;
      r1.z = (u13.x + u23.x + c6) * scale;
      r1.w = (u13.y + u23.y + c7) * scale;
      *reinterpret_cast<float4*>(out + o) = r0;
      *reinterpret_cast<float4*>(out + o + 4) = r1;
    }
  }
}

extern "C" void kernel_launch(void* const* d_in, const int* in_sizes, int n_in,
                              void* d_out, int out_size, void* d_ws,
                              size_t ws_size, hipStream_t stream) {
  const float* ue = (const float*)d_in[0];
  const float* ie = (const float*)d_in[1];
  const float* vals = (const float*)d_in[2];
  const int* rows = (const int*)d_in[3];
  const int* cols = (const int*)d_in[4];

  const int EMB = 64;
  const int n_users = in_sizes[0] / EMB;
  const int n_items = in_sizes[1] / EMB;
  const int n_nodes = n_users + n_items;
  const int E = in_sizes[2];
  const int total_e = n_nodes * EMB;
  const int NC = (n_nodes + CBROWS - 1) >> CSH;  // coarse bins (<=1024)

  // Workspace layout (~152 MB). erec is padded: up to +1 record per row
  // (even alignment) plus 64 slack for spmm's unguarded record reads
  // (cstag follows -- always allocated).
  __half* h0 = (__half*)d_ws;           // ego
  __half* h1 = h0 + total_e;
  __half* h2 = h1 + total_e;
  int2* erec = (int2*)(h2 + total_e);   // final CSR records [E+n_nodes+64]
  int2* cstag = erec + E + n_nodes + 64;  // coarse staging [NC*CAPC]
  int* ccur = (int*)(cstag + (size_t)NC * CAPC);  // cursors [NC] + gcur [1]
  int* gcur = ccur + NC;
  int2* ptr2 = (int2*)(gcur + 8);       // per-row (start,end) [n_nodes]

  const int gP1 = (E + T1 - 1) / T1;
  const int gSpmm = (n_nodes + 3) / 4;

  // --- build ---
  hipMemsetAsync(ccur, 0, (NC + 1) * sizeof(int), stream);
  k_part1<<<gP1, 1024, 0, stream>>>(rows, cols, vals, ccur, cstag, E, ue, ie,
                                    h0, n_users * EMB, total_e);
  k_csr<<<NC, 1024, 0, stream>>>(cstag, ccur, gcur, erec, ptr2, n_nodes);

  // --- propagation; layer 3 fuses the mean + fp32 output write ---
  k_spmm<false><<<gSpmm, 256, 0, stream>>>(h0, h1, nullptr, nullptr, nullptr,
                                           ptr2, erec, n_nodes, 0.f);
  k_spmm<false><<<gSpmm, 256, 0, stream>>>(h1, h2, nullptr, nullptr, nullptr,
                                           ptr2, erec, n_nodes, 0.f);
  k_spmm<true><<<gSpmm, 256, 0, stream>>>(h2, nullptr, h1, h2, (float*)d_out,
                                          ptr2, erec, n_nodes, 1.0f / 3.0f);
}

// Round 9
// 419.367 us; speedup vs baseline: 1.1838x; 1.0041x over previous
//
#include <hip/hip_runtime.h>
#include <hip/hip_fp16.h>

// DimCL encoder, R15.
//  - spmm: unchanged from R14 (branchless masked gather, 8 lanes x int4 per
//    row, consecutive-slot int4 records). At structural floor: FETCH 257MB
//    (compulsory cross-XCD table re-fetch) at ~3.5TB/s miss path.
//  - k_part1: unchanged from R14 (1024 thr, 100% occ, vectorized).
//  - k_csr: register-staged -- records held in named int4 regs (no srec
//    LDS round-trip: deletes 48KB LDS, two LDS passes, one barrier).
//    hist -> scan -> scatter straight from registers to erec.
// Layers fp16, all math fp32.

#define CSH 8             // 256 rows per coarse bin
#define CBROWS (1 << CSH)
#define CAPC 6144         // bin capacity (avg ~5120, ~14 sigma slack)
#define T1 4096           // edges per k_part1 block tile
#define EPT 4             // edges per thread in k_part1 (T1 = 1024*EPT)
#define COLMASK 0x3FFFF   // n_nodes < 2^18

// acc += (float)lo_half(pk) * v   /   acc += (float)hi_half(pk) * v
#define FMAMIX_LO(acc, pk, v)                                             \
  asm("v_fma_mix_f32 %0, %1, %2, %0 op_sel:[0,0,0] op_sel_hi:[1,0,0]"     \
      : "+v"(acc)                                                         \
      : "v"(pk), "v"(v))
#define FMAMIX_HI(acc, pk, v)                                             \
  asm("v_fma_mix_f32 %0, %1, %2, %0 op_sel:[1,0,0] op_sel_hi:[1,0,0]"     \
      : "+v"(acc)                                                         \
      : "v"(pk), "v"(v))

#define FMA8(g, v)                                                        \
  do {                                                                    \
    FMAMIX_LO(c0, (g).x, (v)); FMAMIX_HI(c1, (g).x, (v));                 \
    FMAMIX_LO(c2, (g).y, (v)); FMAMIX_HI(c3, (g).y, (v));                 \
    FMAMIX_LO(c4, (g).z, (v)); FMAMIX_HI(c5, (g).z, (v));                 \
    FMAMIX_LO(c6, (g).w, (v)); FMAMIX_HI(c7, (g).w, (v));                 \
  } while (0)

__device__ __forceinline__ int wave_iscan(int v, int lane) {
#pragma unroll
  for (int off = 1; off < 64; off <<= 1) {
    int t = __shfl_up(v, off, 64);
    if (lane >= off) v += t;
  }
  return v;
}

// Coarse multi-split, 1024 threads: fused ego convert (vectorized), then
// per-block LDS histogram + scan + reserve + reorder, bin-sorted copy-out.
// LDS 48.5KB, 1024 thr -> 2 blocks/CU = 32 waves/CU (100%).
// Requires NC <= 1024 (n_nodes <= 262144).
__global__ __launch_bounds__(1024) void k_part1(
    const int* __restrict__ rows, const int* __restrict__ cols,
    const float* __restrict__ vals, int* __restrict__ ccur,
    int2* __restrict__ cstag, int E,
    const float* __restrict__ ue, const float* __restrict__ ie,
    __half* __restrict__ h0, int nuser_e, int total_e) {
  __shared__ int cnt[1024];   // counts; after reserve: cstag write-idx base
  __shared__ int lcur[1024];
  __shared__ int wsum[16];
  __shared__ int2 sout[T1];
  __shared__ unsigned short sbin[T1];
  int tid = threadIdx.x;
  int lane = tid & 63, wid = tid >> 6;
  int base = blockIdx.x * T1;

  // fused ego init, vectorized: float4 in -> 4x half out (8B store).
  int nq = total_e >> 2;
  for (int i = blockIdx.x * 1024 + tid; i < nq; i += gridDim.x * 1024) {
    int e = i << 2;
    float4 x = (e + 3 < nuser_e)
                   ? *(const float4*)(ue + e)
                   : (e >= nuser_e)
                         ? *(const float4*)(ie + (e - nuser_e))
                         : make_float4(  // straddles user/item boundary
                               (e + 0 < nuser_e) ? ue[e + 0] : ie[e + 0 - nuser_e],
                               (e + 1 < nuser_e) ? ue[e + 1] : ie[e + 1 - nuser_e],
                               (e + 2 < nuser_e) ? ue[e + 2] : ie[e + 2 - nuser_e],
                               (e + 3 < nuser_e) ? ue[e + 3] : ie[e + 3 - nuser_e]);
    __half2 lo = __halves2half2(__float2half(x.x), __float2half(x.y));
    __half2 hi = __halves2half2(__float2half(x.z), __float2half(x.w));
    int2 pk;
    pk.x = *reinterpret_cast<int*>(&lo);
    pk.y = *reinterpret_cast<int*>(&hi);
    *reinterpret_cast<int2*>(h0 + e) = pk;
  }

  cnt[tid] = 0;
  __syncthreads();

  // blocked edge mapping: thread owns edges base+4*tid .. +3 (int4 loads).
  int i0 = base + 4 * tid;
  int rr[EPT], cc[EPT];
  float vv[EPT];
  if (i0 + 3 < E) {
    int4 r4 = *(const int4*)(rows + i0);
    int4 c4 = *(const int4*)(cols + i0);
    float4 v4 = *(const float4*)(vals + i0);
    rr[0] = r4.x; rr[1] = r4.y; rr[2] = r4.z; rr[3] = r4.w;
    cc[0] = c4.x; cc[1] = c4.y; cc[2] = c4.z; cc[3] = c4.w;
    vv[0] = v4.x; vv[1] = v4.y; vv[2] = v4.z; vv[3] = v4.w;
  } else {
#pragma unroll
    for (int k = 0; k < EPT; ++k) {
      int idx = i0 + k;
      rr[k] = (idx < E) ? rows[idx] : -1;
      cc[k] = (idx < E) ? cols[idx] : 0;
      vv[k] = (idx < E) ? vals[idx] : 0.f;
    }
  }
  int recx[EPT], rbin[EPT];
#pragma unroll
  for (int k = 0; k < EPT; ++k) {
    if (rr[k] >= 0) {
      int b = rr[k] >> CSH;
      recx[k] = cc[k] | ((rr[k] & (CBROWS - 1)) << 18);
      rbin[k] = b;
      atomicAdd(&cnt[b], 1);
    } else {
      rbin[k] = -1;
    }
  }
  __syncthreads();

  // exclusive scan of 1024 counters (1 per thread).
  int c0 = cnt[tid];
  int incl = wave_iscan(c0, lane);
  if (lane == 63) wsum[wid] = incl;
  __syncthreads();
  if (wid == 0) {
    int t = (lane < 16) ? wsum[lane] : 0;
    t = wave_iscan(t, lane);
    if (lane < 16) wsum[lane] = t;
  }
  __syncthreads();
  int woff = wid ? wsum[wid - 1] : 0;
  int e0 = incl + woff - c0;  // exclusive offset of bin tid
  lcur[tid] = e0;
  // reserve global range; cnt[tid] becomes direct cstag write-index base
  // (owner-thread read+write only: no hazard).
  int g = (c0 > 0) ? atomicAdd(&ccur[tid], c0) : 0;
  cnt[tid] = tid * CAPC + g - e0;
  __syncthreads();

  // bin-sorted reorder into LDS.
#pragma unroll
  for (int k = 0; k < EPT; ++k) {
    if (rbin[k] >= 0) {
      int p = atomicAdd(&lcur[rbin[k]], 1);
      sout[p] = make_int2(recx[k], __float_as_int(vv[k]));
      sbin[p] = (unsigned short)rbin[k];
    }
  }
  __syncthreads();

  // run-coalesced copy-out: consecutive i -> same bin -> consecutive addrs.
  int m = min(T1, E - base);
  for (int i = tid; i < m; i += 1024) {
    int b = sbin[i];
    int idx = cnt[b] + i;                 // absolute cstag index
    if (idx < (b + 1) * CAPC) cstag[idx] = sout[i];
  }
}

// Fused CSR finalize, register-staged: one block per bin, 1024 threads.
// Each thread holds <=3 int4 (6 records) in NAMED registers (static
// indexing). LDS only for hist/off/lcur (~3KB). hist -> even-aligned scan
// (16B alignment for spmm's int4 record loads; pads never valid) ->
// scatter from regs to erec (bin's contiguous ~40KB chunk, L2-resident) ->
// per-row (start,end) int2.
__global__ __launch_bounds__(1024) void k_csr(
    const int2* __restrict__ cstag, const int* __restrict__ ccur,
    int* __restrict__ gcur, int2* __restrict__ erec,
    int2* __restrict__ ptr2, int n_nodes) {
  __shared__ int hist[CBROWS];
  __shared__ int off[CBROWS];
  __shared__ int lcur[CBROWS];
  __shared__ int sbase;
  int b = blockIdx.x;
  int tid = threadIdx.x;
  int c = min(ccur[b], CAPC);
  if (tid < CBROWS) hist[tid] = 0;
  __syncthreads();
  const int4* p4 = (const int4*)(cstag + (size_t)b * CAPC);
  int nq = (c + 1) >> 1;  // int4 count (<= CAPC/2 = 3072 = 3*1024)
  int i0 = tid, i1 = tid + 1024, i2 = tid + 2048;
  int4 q0 = make_int4(0, 0, 0, 0), q1 = q0, q2 = q0;
  if (i0 < nq) q0 = p4[i0];
  if (i1 < nq) q1 = p4[i1];
  if (i2 < nq) q2 = p4[i2];
  // histogram (guard the second record of a possibly-half int4).
  if (i0 < nq) {
    atomicAdd(&hist[(q0.x >> 18) & (CBROWS - 1)], 1);
    if (2 * i0 + 1 < c) atomicAdd(&hist[(q0.z >> 18) & (CBROWS - 1)], 1);
  }
  if (i1 < nq) {
    atomicAdd(&hist[(q1.x >> 18) & (CBROWS - 1)], 1);
    if (2 * i1 + 1 < c) atomicAdd(&hist[(q1.z >> 18) & (CBROWS - 1)], 1);
  }
  if (i2 < nq) {
    atomicAdd(&hist[(q2.x >> 18) & (CBROWS - 1)], 1);
    if (2 * i2 + 1 < c) atomicAdd(&hist[(q2.z >> 18) & (CBROWS - 1)], 1);
  }
  __syncthreads();
  // exclusive scan of 256 EVEN-ALIGNED counters by wave 0
  // (lane l owns slots 4l..4l+3); lane 63 reserves the bin's global range.
  if (tid < 64) {
    int h0 = hist[4 * tid], h1 = hist[4 * tid + 1];
    int h2 = hist[4 * tid + 2], h3 = hist[4 * tid + 3];
    int a0 = (h0 + 1) & ~1, a1 = (h1 + 1) & ~1;
    int a2 = (h2 + 1) & ~1, a3 = (h3 + 1) & ~1;
    int s = a0 + a1 + a2 + a3;
    int incl = wave_iscan(s, tid);
    int e0 = incl - s;
    off[4 * tid] = e0;
    off[4 * tid + 1] = e0 + a0;
    off[4 * tid + 2] = e0 + a0 + a1;
    off[4 * tid + 3] = e0 + a0 + a1 + a2;
    if (tid == 63) sbase = atomicAdd(gcur, incl);  // incl = even total
  }
  __syncthreads();
  if (tid < CBROWS) lcur[tid] = off[tid];
  __syncthreads();
  int base = sbase;
  // scatter straight from registers (named regs; no dynamic indexing).
  if (i0 < nq) {
    int ro = (q0.x >> 18) & (CBROWS - 1);
    int pos = atomicAdd(&lcur[ro], 1);
    erec[base + pos] = make_int2(q0.x & COLMASK, q0.y);
    if (2 * i0 + 1 < c) {
      int ro2 = (q0.z >> 18) & (CBROWS - 1);
      int pos2 = atomicAdd(&lcur[ro2], 1);
      erec[base + pos2] = make_int2(q0.z & COLMASK, q0.w);
    }
  }
  if (i1 < nq) {
    int ro = (q1.x >> 18) & (CBROWS - 1);
    int pos = atomicAdd(&lcur[ro], 1);
    erec[base + pos] = make_int2(q1.x & COLMASK, q1.y);
    if (2 * i1 + 1 < c) {
      int ro2 = (q1.z >> 18) & (CBROWS - 1);
      int pos2 = atomicAdd(&lcur[ro2], 1);
      erec[base + pos2] = make_int2(q1.z & COLMASK, q1.w);
    }
  }
  if (i2 < nq) {
    int ro = (q2.x >> 18) & (CBROWS - 1);
    int pos = atomicAdd(&lcur[ro], 1);
    erec[base + pos] = make_int2(q2.x & COLMASK, q2.y);
    if (2 * i2 + 1 < c) {
      int ro2 = (q2.z >> 18) & (CBROWS - 1);
      int pos2 = atomicAdd(&lcur[ro2], 1);
      erec[base + pos2] = make_int2(q2.z & COLMASK, q2.w);
    }
  }
  int row = (b << CSH) + tid;
  if (tid < CBROWS && row < n_nodes) {
    int s0 = base + off[tid];
    ptr2[row] = make_int2(s0, s0 + hist[tid]);
  }
}

// Pull-SpMM: one wave per row; lane = slot(0..7) x choct(0..7).
// Slot s owns edges j+4s..j+4s+3 (records 32B contiguous: 2 x int4,
// segments even-aligned). BRANCHLESS: phantom slots' gather offsets masked
// to row 0 (L1-hot), values zeroed -- uniform control flow, 4 gathers in
// flight per lane. 8 fp32 accumulators; 3-level shfl_xor reduction.
// FIN: epilogue fuses (h1+h2+sum)/3, writes fp32 output directly.
// Blocks XCD-swizzled (bijective).
template <bool FIN>
__global__ __launch_bounds__(256) void k_spmm(
    const __half* __restrict__ cur, __half* __restrict__ nxt,
    const __half* __restrict__ h1, const __half* __restrict__ h2,
    float* __restrict__ out, const int2* __restrict__ ptr2,
    const int2* __restrict__ erec, int n, float scale) {
  // bijective XCD swizzle (m204 form): contiguous block ranges per XCD.
  int nwg = gridDim.x;
  int q = nwg >> 3, rr = nwg & 7;
  int xcd = blockIdx.x & 7, idx = blockIdx.x >> 3;
  int swz = (xcd < rr ? xcd * (q + 1) : rr * (q + 1) + (xcd - rr) * q) + idx;
  int w = (swz * 256 + threadIdx.x) >> 6;
  int lane = threadIdx.x & 63;
  if (w >= n) return;
  int2 se = ptr2[w];
  int start = se.x, end = se.y;
  int sub = lane >> 3;        // edge slot 0..7
  int ch = (lane & 7) << 3;   // half-offset within the 64-wide row (16B)
  float c0 = 0.f, c1 = 0.f, c2 = 0.f, c3 = 0.f;
  float c4 = 0.f, c5 = 0.f, c6 = 0.f, c7 = 0.f;
  const int2* eb = erec + 4 * sub;
  for (int j = start; j < end; j += 32) {
    // slot's 4 records, 32B contiguous, 16B-aligned (start even).
    int4 ra = *(const int4*)(eb + j);
    int4 rb = *(const int4*)(eb + j + 2);
    int e0 = j + 4 * sub;
    bool k0 = e0 < end, k1 = e0 + 1 < end;
    bool k2 = e0 + 2 < end, k3 = e0 + 3 < end;
    int o0 = k0 ? (((ra.x & COLMASK) << 6) + ch) : ch;
    int o1 = k1 ? (((ra.z & COLMASK) << 6) + ch) : ch;
    int o2 = k2 ? (((rb.x & COLMASK) << 6) + ch) : ch;
    int o3 = k3 ? (((rb.z & COLMASK) << 6) + ch) : ch;
    float v0 = k0 ? __int_as_float(ra.y) : 0.f;
    float v1 = k1 ? __int_as_float(ra.w) : 0.f;
    float v2 = k2 ? __int_as_float(rb.y) : 0.f;
    float v3 = k3 ? __int_as_float(rb.w) : 0.f;
    int4 g0 = *(const int4*)(cur + o0);
    int4 g1 = *(const int4*)(cur + o1);
    int4 g2 = *(const int4*)(cur + o2);
    int4 g3 = *(const int4*)(cur + o3);
    FMA8(g0, v0);
    FMA8(g1, v1);
    FMA8(g2, v2);
    FMA8(g3, v3);
  }
  // reduce across the 8 slots (lanes with same ch).
  c0 += __shfl_xor(c0, 8, 64); c0 += __shfl_xor(c0, 16, 64); c0 += __shfl_xor(c0, 32, 64);
  c1 += __shfl_xor(c1, 8, 64); c1 += __shfl_xor(c1, 16, 64); c1 += __shfl_xor(c1, 32, 64);
  c2 += __shfl_xor(c2, 8, 64); c2 += __shfl_xor(c2, 16, 64); c2 += __shfl_xor(c2, 32, 64);
  c3 += __shfl_xor(c3, 8, 64); c3 += __shfl_xor(c3, 16, 64); c3 += __shfl_xor(c3, 32, 64);
  c4 += __shfl_xor(c4, 8, 64); c4 += __shfl_xor(c4, 16, 64); c4 += __shfl_xor(c4, 32, 64);
  c5 += __shfl_xor(c5, 8, 64); c5 += __shfl_xor(c5, 16, 64); c5 += __shfl_xor(c5, 32, 64);
  c6 += __shfl_xor(c6, 8, 64); c6 += __shfl_xor(c6, 16, 64); c6 += __shfl_xor(c6, 32, 64);
  c7 += __shfl_xor(c7, 8, 64); c7 += __shfl_xor(c7, 16, 64); c7 += __shfl_xor(c7, 32, 64);
  if (sub == 0) {
    size_t o = ((size_t)w << 6) + ch;
    if (!FIN) {
      __half2 p0 = __halves2half2(__float2half(c0), __float2half(c1));
      __half2 p1 = __halves2half2(__float2half(c2), __float2half(c3));
      __half2 p2 = __halves2half2(__float2half(c4), __float2half(c5));
      __half2 p3 = __halves2half2(__float2half(c6), __float2half(c7));
      int4 pk;
      pk.x = *reinterpret_cast<int*>(&p0);
      pk.y = *reinterpret_cast<int*>(&p1);
      pk.z = *reinterpret_cast<int*>(&p2);
      pk.w = *reinterpret_cast<int*>(&p3);
      *reinterpret_cast<int4*>(nxt + o) = pk;
    } else {
      int4 x1 = *(const int4*)(h1 + o);
      int4 x2 = *(const int4*)(h2 + o);
      float2 u10 = __half22float2(*reinterpret_cast<__half2*>(&x1.x));
      float2 u11 = __half22float2(*reinterpret_cast<__half2*>(&x1.y));
      float2 u12 = __half22float2(*reinterpret_cast<__half2*>(&x1.z));
      float2 u13 = __half22float2(*reinterpret_cast<__half2*>(&x1.w));
      float2 u20 = __half22float2(*reinterpret_cast<__half2*>(&x2.x));
      float2 u21 = __half22float2(*reinterpret_cast<__half2*>(&x2.y));
      float2 u22 = __half22float2(*reinterpret_cast<__half2*>(&x2.z));
      float2 u23 = __half22float2(*reinterpret_cast<__half2*>(&x2.w));
      float4 r0, r1;
      r0.x = (u10.x + u20.x + c0) * scale;
      r0.y = (u10.y + u20.y + c1) * scale;
      r0.z = (u11.x + u21.x + c2) * scale;
      r0.w = (u11.y + u21.y + c3) * scale;
      r1.x = (u12.x + u22.x + c4) * scale;
      r1.y = (u12.y + u22.y + c5) * scale;
      r1.z = (u13.x + u23.x + c6) * scale;
      r1.w = (u13.y + u23.y + c7) * scale;
      *reinterpret_cast<float4*>(out + o) = r0;
      *reinterpret_cast<float4*>(out + o + 4) = r1;
    }
  }
}

extern "C" void kernel_launch(void* const* d_in, const int* in_sizes, int n_in,
                              void* d_out, int out_size, void* d_ws,
                              size_t ws_size, hipStream_t stream) {
  const float* ue = (const float*)d_in[0];
  const float* ie = (const float*)d_in[1];
  const float* vals = (const float*)d_in[2];
  const int* rows = (const int*)d_in[3];
  const int* cols = (const int*)d_in[4];

  const int EMB = 64;
  const int n_users = in_sizes[0] / EMB;
  const int n_items = in_sizes[1] / EMB;
  const int n_nodes = n_users + n_items;
  const int E = in_sizes[2];
  const int total_e = n_nodes * EMB;
  const int NC = (n_nodes + CBROWS - 1) >> CSH;  // coarse bins (<=1024)

  // Workspace layout (~152 MB). erec is padded: up to +1 record per row
  // (even alignment) plus 64 slack for spmm's unguarded record reads
  // (cstag follows -- always allocated).
  __half* h0 = (__half*)d_ws;           // ego
  __half* h1 = h0 + total_e;
  __half* h2 = h1 + total_e;
  int2* erec = (int2*)(h2 + total_e);   // final CSR records [E+n_nodes+64]
  int2* cstag = erec + E + n_nodes + 64;  // coarse staging [NC*CAPC]
  int* ccur = (int*)(cstag + (size_t)NC * CAPC);  // cursors [NC] + gcur [1]
  int* gcur = ccur + NC;
  int2* ptr2 = (int2*)(gcur + 8);       // per-row (start,end) [n_nodes]

  const int gP1 = (E + T1 - 1) / T1;
  const int gSpmm = (n_nodes + 3) / 4;

  // --- build ---
  hipMemsetAsync(ccur, 0, (NC + 1) * sizeof(int), stream);
  k_part1<<<gP1, 1024, 0, stream>>>(rows, cols, vals, ccur, cstag, E, ue, ie,
                                    h0, n_users * EMB, total_e);
  k_csr<<<NC, 1024, 0, stream>>>(cstag, ccur, gcur, erec, ptr2, n_nodes);

  // --- propagation; layer 3 fuses the mean + fp32 output write ---
  k_spmm<false><<<gSpmm, 256, 0, stream>>>(h0, h1, nullptr, nullptr, nullptr,
                                           ptr2, erec, n_nodes, 0.f);
  k_spmm<false><<<gSpmm, 256, 0, stream>>>(h1, h2, nullptr, nullptr, nullptr,
                                           ptr2, erec, n_nodes, 0.f);
  k_spmm<true><<<gSpmm, 256, 0, stream>>>(h2, nullptr, h1, h2, (float*)d_out,
                                          ptr2, erec, n_nodes, 1.0f / 3.0f);
}